// Round 6
// baseline (81.948 us; speedup 1.0000x reference)
//
#include <hip/hip_runtime.h>
#include <cfloat>
#include <math.h>

#define NB   16
#define NGT  60
#define NA   8400
#define KNN  10
#define NCAND (NGT*KNN)   // 600
#define EPSF 1e-7f
#define PIF  3.14159265358979f
#define FOCAL_BLOCKS 2048

// vec4 index space over (p0,p1,p2) concatenated: 2,822,400 vec4s total.
// multiples of 21 are row starts (box channels) -> decode; rest -> focal.
#define NV0   2150400u   // p0 vec4s: 16*6400*21
#define NV1    537600u   // p1
#define NV2    134400u   // p2
#define NVTOT 2822400u
#define NROWS  134400u   // 16*8400
#define FOCAL_COUNT 2688000u  // NVTOT - NROWS

#define LOG2E 1.44269504088896341f
#define LN2   0.69314718055994531f

__device__ __forceinline__ float fexp2(float x){ return __builtin_amdgcn_exp2f(x); }
__device__ __forceinline__ float flog2(float x){ return __builtin_amdgcn_logf(x); }
__device__ __forceinline__ float frcp (float x){ return __builtin_amdgcn_rcpf(x); }

__device__ __forceinline__ float fsigm(float x){
  return frcp(1.0f + fexp2(-x*LOG2E));
}
__device__ __forceinline__ float fsoftplus(float x){
  float u = fexp2(-fabsf(x)*LOG2E);
  return fmaxf(x,0.f) + LN2*flog2(1.0f + u);
}
// fbg = softplus(x)*sigmoid(x)^2 = (x + ln(1+u)) / (1+u)^2,  u = e^-x
__device__ __forceinline__ float fbg(float x){
  float u = fexp2(fminf(-x*LOG2E, 126.0f));
  float t = frcp(1.0f + u);
  return (x + LN2*flog2(1.0f + u)) * t * t;
}

template<int S, int BASE, int STRIDE_I>
__device__ __forceinline__ void decode_row(const float* __restrict__ p, unsigned row,
                                           float4* __restrict__ boxes){
  unsigned img   = row / (unsigned)(S*S);
  unsigned local = row - img*(unsigned)(S*S);
  unsigned i = local / (unsigned)S, j = local - i*(unsigned)S;
  float4 x4 = *(const float4*)(p + (size_t)row*84u);
  const float stf = (float)STRIDE_I;
  float px = (fsigm(x4.x)*2.f - 0.5f + (float)j)*stf;
  float py = (fsigm(x4.y)*2.f - 0.5f + (float)i)*stf;
  float pw = fsoftplus(x4.z)*stf;
  float ph = fsoftplus(x4.w)*stf;
  boxes[(size_t)img*NA + BASE + local] = make_float4(px,py,pw,ph);
}

// streaming pass, divergence-free: focal over class vec4s (index-remapped to
// skip row starts), decode over row starts as a separate index range
__global__ __launch_bounds__(256) void fused_decode_focal(const float* __restrict__ p0,
                                                          const float* __restrict__ p1,
                                                          const float* __restrict__ p2,
                                                          float4* __restrict__ boxes,
                                                          float* __restrict__ fsum,
                                                          int* __restrict__ done){
  if (blockIdx.x == 0 && threadIdx.x == 0) *done = 0;
  __shared__ float sbuf[4];
  float sum = 0.f;
  unsigned stride = gridDim.x*blockDim.x;
  for (unsigned u = blockIdx.x*blockDim.x + threadIdx.x; u < NVTOT; u += stride){
    if (u < FOCAL_COUNT){
      // class vec4: v = 21*(u/20) + u%20 + 1  (never a multiple of 21)
      unsigned g = u / 20u;
      unsigned v = 21u*g + (u - 20u*g) + 1u;
      const float* p; unsigned vloc;
      if (v < NV0)           { p=p0; vloc = v; }
      else if (v < NV0+NV1)  { p=p1; vloc = v - NV0; }
      else                   { p=p2; vloc = v - (NV0+NV1); }
      float4 x4 = *(const float4*)(p + (size_t)vloc*4u);
      sum += fbg(x4.x) + fbg(x4.y) + fbg(x4.z) + fbg(x4.w);
    } else {
      unsigned row = u - FOCAL_COUNT;
      if (row < 102400u)      decode_row<80,    0,  8>(p0, row,           boxes);
      else if (row < 128000u) decode_row<40, 6400, 16>(p1, row - 102400u, boxes);
      else                    decode_row<20, 8000, 32>(p2, row - 128000u, boxes);
    }
  }
  sum *= 0.75f;
  #pragma unroll
  for (int off=32; off>0; off>>=1) sum += __shfl_xor(sum, off);
  int wid = threadIdx.x >> 6;
  if ((threadIdx.x & 63) == 0) sbuf[wid] = sum;
  __syncthreads();
  if (threadIdx.x == 0) fsum[blockIdx.x] = sbuf[0]+sbuf[1]+sbuf[2]+sbuf[3];
}

__device__ __forceinline__ const float* anchor_base(const float* p0,const float* p1,const float* p2,int img,int a){
  if (a < 6400) return p0 + (size_t)(img*6400 + a)*84;
  if (a < 8000) return p1 + (size_t)(img*1600 + (a-6400))*84;
  return p2 + (size_t)(img*400 + (a-8000))*84;
}

// one wave per (img,gt), 4 waves/block. Exact top-10 from pruned windows:
// 13x13 (L0) + 7x7 (L1) + 5x5 (L2) = 243 candidates. d10 <= 1568 provably;
// anything outside the windows has min-possible dist^2 > 1568.
__global__ __launch_bounds__(256) void topk_kernel(const float4* __restrict__ boxes,
                                                   const float* __restrict__ gt,
                                                   int* __restrict__ cand){
  int wid  = threadIdx.x >> 6;
  int lane = threadIdx.x & 63;
  int pair = blockIdx.x*4 + wid;          // 0..959
  int img = pair / NGT, g = pair - img*NGT;
  const float* gb = gt + (size_t)(img*NGT + g)*4;
  float tcx = (gb[0]+gb[2])*0.5f, tcy = (gb[1]+gb[3])*0.5f;

  int jx0 = (int)(tcx * 0.125f),   iy0 = (int)(tcy * 0.125f);
  int jx1 = (int)(tcx * 0.0625f),  iy1 = (int)(tcy * 0.0625f);
  int jx2 = (int)(tcx * 0.03125f), iy2 = (int)(tcy * 0.03125f);

  const float4* bb = boxes + (size_t)img*NA;

  float d0=FLT_MAX,d1=FLT_MAX,d2=FLT_MAX,d3=FLT_MAX;
  int   a0,a1,a2,a3;
  #pragma unroll
  for (int s=0; s<4; s++){
    int c = lane + 64*s;
    float dd = FLT_MAX; int aa = 9000000 + c;
    int i, j, S, base, valid = 1;
    if (c < 169)      { int r=c/13,  q=c-13*r;           i=iy0-6+r; j=jx0-6+q; S=80; base=0; }
    else if (c < 218) { int t=c-169; int r=t/7, q=t-7*r; i=iy1-3+r; j=jx1-3+q; S=40; base=6400; }
    else if (c < 243) { int t=c-218; int r=t/5, q=t-5*r; i=iy2-2+r; j=jx2-2+q; S=20; base=8000; }
    else { valid = 0; i=j=0; S=1; base=0; }
    if (valid && i>=0 && i<S && j>=0 && j<S){
      int anchor = base + i*S + j;
      float4 b = bb[anchor];
      float dx=b.x-tcx, dy=b.y-tcy;
      dd = dx*dx + dy*dy;
      aa = anchor;
    }
    if (s==0){ d0=dd; a0=aa; } else if (s==1){ d1=dd; a1=aa; }
    else if (s==2){ d2=dd; a2=aa; } else { d3=dd; a3=aa; }
  }

  for (int r=0; r<KNN; r++){
    float v = d0; int anc = a0;
    if (d1 < v || (d1==v && a1<anc)){ v=d1; anc=a1; }
    if (d2 < v || (d2==v && a2<anc)){ v=d2; anc=a2; }
    if (d3 < v || (d3==v && a3<anc)){ v=d3; anc=a3; }
    #pragma unroll
    for (int off=32; off>0; off>>=1){
      float v2 = __shfl_xor(v, off);
      int  A2 = __shfl_xor(anc, off);
      if (v2 < v || (v2==v && A2<anc)){ v=v2; anc=A2; }
    }
    if (a0==anc) d0=FLT_MAX;
    if (a1==anc) d1=FLT_MAX;
    if (a2==anc) d2=FLT_MAX;
    if (a3==anc) d3=FLT_MAX;
    if (lane == 0) cand[(size_t)pair*KNN + r] = anc;
  }
}

// one BLOCK per (img,gt): cost argmin; the LAST block to finish also runs the
// tail (ciou + dedup'd corrections + focal partial reduction + final scalar)
__global__ __launch_bounds__(256) void match_tail_kernel(const float4* __restrict__ boxes,
                                                         const int* __restrict__ cand,
                                                         const float* __restrict__ gt,
                                                         const int* __restrict__ labels,
                                                         const float* __restrict__ p0,
                                                         const float* __restrict__ p1,
                                                         const float* __restrict__ p2,
                                                         int* __restrict__ matched,
                                                         const float* __restrict__ fsum,
                                                         int* __restrict__ done,
                                                         float* __restrict__ out){
  int pair = blockIdx.x;
  int img = pair / NGT, j = pair - img*NGT;
  int tid = threadIdx.x;
  int wid = tid >> 6, lane = tid & 63;
  {
    const float* gb = gt + (size_t)(img*NGT + j)*4;
    float gx=gb[0], gy=gb[1], gz=gb[2], gw=gb[3];
    float a2 = fmaxf(gz-gx,0.f)*fmaxf(gw-gy,0.f);
    int lab = labels[img*NGT + j];

    const int* ci = cand + (size_t)img*NCAND;
    float best = FLT_MAX; int bslot = 1<<30; int banchor = -1;
    for (int c=tid; c<NCAND; c+=256){
      int a = ci[c];
      float4 b = boxes[(size_t)img*NA + a];
      float bx1=b.x-b.z*0.5f, by1=b.y-b.w*0.5f, bx2=b.x+b.z*0.5f, by2=b.y+b.w*0.5f;
      float a1 = fmaxf(bx2-bx1,0.f)*fmaxf(by2-by1,0.f);
      float ix1=fmaxf(bx1,gx), iy1=fmaxf(by1,gy);
      float ix2=fminf(bx2,gz), iy2=fminf(by2,gw);
      float inter = fmaxf(ix2-ix1,0.f)*fmaxf(iy2-iy1,0.f);
      float uni = a1 + a2 - inter + EPSF;
      float iou = fminf(fmaxf(inter/uni,0.f),1.f);
      float lg = anchor_base(p0,p1,p2,img,a)[4+lab];
      float cost = 0.5f*(1.f - fsigm(lg)) + 6.f*(1.f - iou);
      if (cost < best){ best=cost; bslot=c; banchor=a; }
    }
    #pragma unroll
    for (int off=32; off>0; off>>=1){
      float v2 = __shfl_xor(best, off);
      int  s2 = __shfl_xor(bslot, off);
      int  a2s= __shfl_xor(banchor, off);
      if (v2 < best || (v2==best && s2<bslot)){ best=v2; bslot=s2; banchor=a2s; }
    }
    __shared__ float bc[4]; __shared__ int bs[4], ba[4];
    if (lane == 0){ bc[wid]=best; bs[wid]=bslot; ba[wid]=banchor; }
    __syncthreads();
    if (tid == 0){
      float v=bc[0]; int s=bs[0]; int a=ba[0];
      #pragma unroll
      for (int k=1;k<4;k++){
        if (bc[k] < v || (bc[k]==v && bs[k]<s)){ v=bc[k]; s=bs[k]; a=ba[k]; }
      }
      matched[img*NGT + j] = a;
    }
  }

  // ---- last-block-done: the final block runs the tail ----
  __shared__ int lastflag;
  if (tid == 0){
    __threadfence();                       // publish matched[pair]
    int old = atomicAdd(done, 1);
    lastflag = (old == NB*NGT - 1);
  }
  __syncthreads();
  if (!lastflag) return;
  __threadfence();                         // acquire all matched[] writes

  __shared__ int sm[NB*NGT];
  __shared__ int sl[NB*NGT];
  for (int t=tid; t<NB*NGT; t+=256){ sm[t]=matched[t]; sl[t]=labels[t]; }
  __syncthreads();

  float local_box = 0.f, local_corr = 0.f;
  #pragma unroll
  for (int q=0; q<4; q++){
    int im = wid*4 + q;                    // wave wid handles 4 images
    if (lane < NGT){
      int jj = lane;
      int m = sm[im*NGT + jj];
      float4 pb = boxes[(size_t)im*NA + m];
      float px1=pb.x-pb.z*0.5f, py1=pb.y-pb.w*0.5f, px2=pb.x+pb.z*0.5f, py2=pb.y+pb.w*0.5f;
      const float* gb = gt + (size_t)(im*NGT + jj)*4;
      float gx=gb[0], gy=gb[1], gz=gb[2], gw=gb[3];
      float pw=fmaxf(px2-px1,EPSF), ph=fmaxf(py2-py1,EPSF);
      float tw=fmaxf(gz-gx,EPSF),  th=fmaxf(gw-gy,EPSF);
      float inter = fmaxf(fminf(px2,gz)-fmaxf(px1,gx),0.f)*fmaxf(fminf(py2,gw)-fmaxf(py1,gy),0.f);
      float uni = pw*ph + tw*th - inter + EPSF;
      float iou = inter/uni;
      float dcx = (px1+px2)*0.5f - (gx+gz)*0.5f;
      float dcy = (py1+py2)*0.5f - (gy+gw)*0.5f;
      float cd = dcx*dcx + dcy*dcy;
      float cw = fmaxf(px2,gz) - fminf(px1,gx);
      float ch = fmaxf(py2,gw) - fminf(py1,gy);
      float c2 = cw*cw + ch*ch + EPSF;
      float dv = atanf(tw/th) - atanf(pw/ph);
      float v  = (4.f/(PIF*PIF))*dv*dv;
      float alpha = v/(v - iou + 1.f + EPSF);
      float ciou = iou - cd/c2 - alpha*v;
      local_box += 1.f - ciou;

      int lab = sl[im*NGT + jj];
      bool dup = false;
      for (int j2=0; j2<jj; j2++)
        if (sm[im*NGT + j2]==m && sl[im*NGT + j2]==lab){ dup=true; break; }
      if (!dup){
        float x = anchor_base(p0,p1,p2,im,m)[4+lab];
        float s  = fsigm(x);
        float u  = fexp2(-fabsf(x)*LOG2E);
        float lt = LN2*flog2(1.0f + u);
        float sp_pos = fmaxf(-x,0.f) + lt;   // ce for tgt=1
        float sp_neg = fmaxf( x,0.f) + lt;   // ce for tgt=0
        local_corr += 0.25f*sp_pos*(1.f-s)*(1.f-s) - 0.75f*sp_neg*s*s;
      }
    }
  }
  float local_f = 0.f;
  #pragma unroll
  for (int k=0; k<FOCAL_BLOCKS/256; k++) local_f += fsum[tid + 256*k];

  #pragma unroll
  for (int off=32; off>0; off>>=1){
    local_box  += __shfl_xor(local_box,  off);
    local_corr += __shfl_xor(local_corr, off);
    local_f    += __shfl_xor(local_f,    off);
  }
  __shared__ float wb[4], wc[4], wf[4];
  if (lane == 0){ wb[wid]=local_box; wc[wid]=local_corr; wf[wid]=local_f; }
  __syncthreads();
  if (tid == 0){
    float sb=0.f, sc=0.f, sf=0.f;
    #pragma unroll
    for (int k=0;k<4;k++){ sb+=wb[k]; sc+=wc[k]; sf+=wf[k]; }
    out[0] = (7.5f*sb + 0.5f*(sf + sc)) / (60.f*16.f);
  }
}

extern "C" void kernel_launch(void* const* d_in, const int* in_sizes, int n_in,
                              void* d_out, int out_size, void* d_ws, size_t ws_size,
                              hipStream_t stream){
  const float* p0 = (const float*)d_in[0];
  const float* p1 = (const float*)d_in[1];
  const float* p2 = (const float*)d_in[2];
  const float* gt = (const float*)d_in[3];
  const int* labels = (const int*)d_in[4];
  float* out = (float*)d_out;

  float4* boxes   = (float4*)d_ws;                                        // 2.15 MB
  int*    cand    = (int*)((char*)d_ws + (size_t)NB*NA*sizeof(float4));   // 38.4 KB
  int*    matched = (int*)((char*)cand + (size_t)NB*NCAND*sizeof(int));   // 3.8 KB
  float*  fsum    = (float*)((char*)matched + (size_t)NB*NGT*sizeof(int));// 8 KB
  int*    done    = (int*)((char*)fsum + FOCAL_BLOCKS*sizeof(float));     // 4 B

  fused_decode_focal<<<FOCAL_BLOCKS, 256, 0, stream>>>(p0, p1, p2, boxes, fsum, done);
  topk_kernel<<<NB*NGT/4, 256, 0, stream>>>(boxes, gt, cand);
  match_tail_kernel<<<NB*NGT, 256, 0, stream>>>(boxes, cand, gt, labels, p0, p1, p2,
                                                matched, fsum, done, out);
}

// Round 7
// 46.472 us; speedup vs baseline: 1.7634x; 1.7634x over previous
//
#include <hip/hip_runtime.h>
#include <cfloat>
#include <math.h>

#define NB   16
#define NGT  60
#define NA   8400
#define KNN  10
#define NCAND (NGT*KNN)   // 600
#define EPSF 1e-7f
#define PIF  3.14159265358979f
#define FOCAL_BLOCKS 2048

// vec4 index space over (p0,p1,p2) concatenated: 2,822,400 vec4s total.
// multiples of 21 are row starts (box channels) -> decode; rest -> focal.
#define NV0   2150400u   // p0 vec4s: 16*6400*21
#define NV1    537600u   // p1
#define NV2    134400u   // p2
#define NVTOT 2822400u
#define NROWS  134400u   // 16*8400
#define FOCAL_COUNT 2688000u  // NVTOT - NROWS

#define LOG2E 1.44269504088896341f
#define LN2   0.69314718055994531f

__device__ __forceinline__ float fexp2(float x){ return __builtin_amdgcn_exp2f(x); }
__device__ __forceinline__ float flog2(float x){ return __builtin_amdgcn_logf(x); }
__device__ __forceinline__ float frcp (float x){ return __builtin_amdgcn_rcpf(x); }

__device__ __forceinline__ float fsigm(float x){
  return frcp(1.0f + fexp2(-x*LOG2E));
}
__device__ __forceinline__ float fsoftplus(float x){
  float u = fexp2(-fabsf(x)*LOG2E);
  return fmaxf(x,0.f) + LN2*flog2(1.0f + u);
}
// fbg = softplus(x)*sigmoid(x)^2 = (x + ln(1+u)) / (1+u)^2,  u = e^-x
__device__ __forceinline__ float fbg(float x){
  float u = fexp2(fminf(-x*LOG2E, 126.0f));
  float t = frcp(1.0f + u);
  return (x + LN2*flog2(1.0f + u)) * t * t;
}

template<int S, int BASE, int STRIDE_I>
__device__ __forceinline__ void decode_row(const float* __restrict__ p, unsigned row,
                                           float4* __restrict__ boxes){
  unsigned img   = row / (unsigned)(S*S);
  unsigned local = row - img*(unsigned)(S*S);
  unsigned i = local / (unsigned)S, j = local - i*(unsigned)S;
  float4 x4 = *(const float4*)(p + (size_t)row*84u);
  const float stf = (float)STRIDE_I;
  float px = (fsigm(x4.x)*2.f - 0.5f + (float)j)*stf;
  float py = (fsigm(x4.y)*2.f - 0.5f + (float)i)*stf;
  float pw = fsoftplus(x4.z)*stf;
  float ph = fsoftplus(x4.w)*stf;
  boxes[(size_t)img*NA + BASE + local] = make_float4(px,py,pw,ph);
}

// streaming pass, divergence-free: focal over class vec4s (index-remapped to
// skip row starts), decode over row starts as a separate index range
__global__ __launch_bounds__(256) void fused_decode_focal(const float* __restrict__ p0,
                                                          const float* __restrict__ p1,
                                                          const float* __restrict__ p2,
                                                          float4* __restrict__ boxes,
                                                          float* __restrict__ fsum){
  __shared__ float sbuf[4];
  float sum = 0.f;
  unsigned stride = gridDim.x*blockDim.x;
  for (unsigned u = blockIdx.x*blockDim.x + threadIdx.x; u < NVTOT; u += stride){
    if (u < FOCAL_COUNT){
      // class vec4: v = 21*(u/20) + u%20 + 1  (never a multiple of 21)
      unsigned g = u / 20u;
      unsigned v = 21u*g + (u - 20u*g) + 1u;
      const float* p; unsigned vloc;
      if (v < NV0)           { p=p0; vloc = v; }
      else if (v < NV0+NV1)  { p=p1; vloc = v - NV0; }
      else                   { p=p2; vloc = v - (NV0+NV1); }
      float4 x4 = *(const float4*)(p + (size_t)vloc*4u);
      sum += fbg(x4.x) + fbg(x4.y) + fbg(x4.z) + fbg(x4.w);
    } else {
      unsigned row = u - FOCAL_COUNT;
      if (row < 102400u)      decode_row<80,    0,  8>(p0, row,           boxes);
      else if (row < 128000u) decode_row<40, 6400, 16>(p1, row - 102400u, boxes);
      else                    decode_row<20, 8000, 32>(p2, row - 128000u, boxes);
    }
  }
  sum *= 0.75f;
  #pragma unroll
  for (int off=32; off>0; off>>=1) sum += __shfl_xor(sum, off);
  int wid = threadIdx.x >> 6;
  if ((threadIdx.x & 63) == 0) sbuf[wid] = sum;
  __syncthreads();
  if (threadIdx.x == 0) fsum[blockIdx.x] = sbuf[0]+sbuf[1]+sbuf[2]+sbuf[3];
}

__device__ __forceinline__ const float* anchor_base(const float* p0,const float* p1,const float* p2,int img,int a){
  if (a < 6400) return p0 + (size_t)(img*6400 + a)*84;
  if (a < 8000) return p1 + (size_t)(img*1600 + (a-6400))*84;
  return p2 + (size_t)(img*400 + (a-8000))*84;
}

// one wave per (img,gt), 4 waves/block. Exact top-10 from pruned windows:
// 13x13 (L0) + 7x7 (L1) + 5x5 (L2) = 243 candidates. d10 <= 1568 provably;
// anything outside the windows has min-possible dist^2 > 1568.
__global__ __launch_bounds__(256) void topk_kernel(const float4* __restrict__ boxes,
                                                   const float* __restrict__ gt,
                                                   int* __restrict__ cand){
  int wid  = threadIdx.x >> 6;
  int lane = threadIdx.x & 63;
  int pair = blockIdx.x*4 + wid;          // 0..959
  int img = pair / NGT, g = pair - img*NGT;
  const float* gb = gt + (size_t)(img*NGT + g)*4;
  float tcx = (gb[0]+gb[2])*0.5f, tcy = (gb[1]+gb[3])*0.5f;

  int jx0 = (int)(tcx * 0.125f),   iy0 = (int)(tcy * 0.125f);
  int jx1 = (int)(tcx * 0.0625f),  iy1 = (int)(tcy * 0.0625f);
  int jx2 = (int)(tcx * 0.03125f), iy2 = (int)(tcy * 0.03125f);

  const float4* bb = boxes + (size_t)img*NA;

  float d0=FLT_MAX,d1=FLT_MAX,d2=FLT_MAX,d3=FLT_MAX;
  int   a0,a1,a2,a3;
  #pragma unroll
  for (int s=0; s<4; s++){
    int c = lane + 64*s;
    float dd = FLT_MAX; int aa = 9000000 + c;
    int i, j, S, base, valid = 1;
    if (c < 169)      { int r=c/13,  q=c-13*r;           i=iy0-6+r; j=jx0-6+q; S=80; base=0; }
    else if (c < 218) { int t=c-169; int r=t/7, q=t-7*r; i=iy1-3+r; j=jx1-3+q; S=40; base=6400; }
    else if (c < 243) { int t=c-218; int r=t/5, q=t-5*r; i=iy2-2+r; j=jx2-2+q; S=20; base=8000; }
    else { valid = 0; i=j=0; S=1; base=0; }
    if (valid && i>=0 && i<S && j>=0 && j<S){
      int anchor = base + i*S + j;
      float4 b = bb[anchor];
      float dx=b.x-tcx, dy=b.y-tcy;
      dd = dx*dx + dy*dy;
      aa = anchor;
    }
    if (s==0){ d0=dd; a0=aa; } else if (s==1){ d1=dd; a1=aa; }
    else if (s==2){ d2=dd; a2=aa; } else { d3=dd; a3=aa; }
  }

  for (int r=0; r<KNN; r++){
    float v = d0; int anc = a0;
    if (d1 < v || (d1==v && a1<anc)){ v=d1; anc=a1; }
    if (d2 < v || (d2==v && a2<anc)){ v=d2; anc=a2; }
    if (d3 < v || (d3==v && a3<anc)){ v=d3; anc=a3; }
    #pragma unroll
    for (int off=32; off>0; off>>=1){
      float v2 = __shfl_xor(v, off);
      int  A2 = __shfl_xor(anc, off);
      if (v2 < v || (v2==v && A2<anc)){ v=v2; anc=A2; }
    }
    if (a0==anc) d0=FLT_MAX;
    if (a1==anc) d1=FLT_MAX;
    if (a2==anc) d2=FLT_MAX;
    if (a3==anc) d3=FLT_MAX;
    if (lane == 0) cand[(size_t)pair*KNN + r] = anc;
  }
}

// one BLOCK per (img,gt): 256 threads scan 600 candidates
__global__ __launch_bounds__(256) void match_kernel(const float4* __restrict__ boxes,
                                                    const int* __restrict__ cand,
                                                    const float* __restrict__ gt,
                                                    const int* __restrict__ labels,
                                                    const float* __restrict__ p0,
                                                    const float* __restrict__ p1,
                                                    const float* __restrict__ p2,
                                                    int* __restrict__ matched){
  int pair = blockIdx.x;
  int img = pair / NGT, j = pair - img*NGT;
  int tid = threadIdx.x;
  int wid = tid >> 6, lane = tid & 63;
  const float* gb = gt + (size_t)(img*NGT + j)*4;
  float gx=gb[0], gy=gb[1], gz=gb[2], gw=gb[3];
  float a2 = fmaxf(gz-gx,0.f)*fmaxf(gw-gy,0.f);
  int lab = labels[img*NGT + j];

  const int* ci = cand + (size_t)img*NCAND;
  float best = FLT_MAX; int bslot = 1<<30; int banchor = -1;
  for (int c=tid; c<NCAND; c+=256){
    int a = ci[c];
    float4 b = boxes[(size_t)img*NA + a];
    float bx1=b.x-b.z*0.5f, by1=b.y-b.w*0.5f, bx2=b.x+b.z*0.5f, by2=b.y+b.w*0.5f;
    float a1 = fmaxf(bx2-bx1,0.f)*fmaxf(by2-by1,0.f);
    float ix1=fmaxf(bx1,gx), iy1=fmaxf(by1,gy);
    float ix2=fminf(bx2,gz), iy2=fminf(by2,gw);
    float inter = fmaxf(ix2-ix1,0.f)*fmaxf(iy2-iy1,0.f);
    float uni = a1 + a2 - inter + EPSF;
    float iou = fminf(fmaxf(inter/uni,0.f),1.f);
    float lg = anchor_base(p0,p1,p2,img,a)[4+lab];
    float cost = 0.5f*(1.f - fsigm(lg)) + 6.f*(1.f - iou);
    if (cost < best){ best=cost; bslot=c; banchor=a; }
  }
  #pragma unroll
  for (int off=32; off>0; off>>=1){
    float v2 = __shfl_xor(best, off);
    int  s2 = __shfl_xor(bslot, off);
    int  a2s= __shfl_xor(banchor, off);
    if (v2 < best || (v2==best && s2<bslot)){ best=v2; bslot=s2; banchor=a2s; }
  }
  __shared__ float bc[4]; __shared__ int bs[4], ba[4];
  if (lane == 0){ bc[wid]=best; bs[wid]=bslot; ba[wid]=banchor; }
  __syncthreads();
  if (tid == 0){
    float v=bc[0]; int s=bs[0]; int a=ba[0];
    #pragma unroll
    for (int k=1;k<4;k++){
      if (bc[k] < v || (bc[k]==v && bs[k]<s)){ v=bc[k]; s=bs[k]; a=ba[k]; }
    }
    matched[img*NGT + j] = a;
  }
}

// single block, 16 waves (one image each): ciou + dedup'd corrections + focal
// partial reduction + final scalar
__global__ __launch_bounds__(1024) void tail_kernel(const float4* __restrict__ boxes,
                                                    const int* __restrict__ matched_g,
                                                    const float* __restrict__ gt,
                                                    const int* __restrict__ labels,
                                                    const float* __restrict__ p0,
                                                    const float* __restrict__ p1,
                                                    const float* __restrict__ p2,
                                                    const float* __restrict__ fsum,
                                                    float* __restrict__ out){
  int tid = threadIdx.x;
  int wid = tid >> 6;        // image
  int lane = tid & 63;
  __shared__ int sm[NB][NGT];
  __shared__ int sl[NB][NGT];
  __shared__ float wb[NB], wc[NB], wf[NB];
  if (lane < NGT){
    sm[wid][lane] = matched_g[wid*NGT + lane];
    sl[wid][lane] = labels[wid*NGT + lane];
  }
  __syncthreads();

  int img = wid;
  float local_box = 0.f, local_corr = 0.f;
  if (lane < NGT){
    int j = lane;
    int m = sm[img][j];
    float4 pb = boxes[(size_t)img*NA + m];
    float px1=pb.x-pb.z*0.5f, py1=pb.y-pb.w*0.5f, px2=pb.x+pb.z*0.5f, py2=pb.y+pb.w*0.5f;
    const float* gb = gt + (size_t)(img*NGT + j)*4;
    float gx=gb[0], gy=gb[1], gz=gb[2], gw=gb[3];
    float pw=fmaxf(px2-px1,EPSF), ph=fmaxf(py2-py1,EPSF);
    float tw=fmaxf(gz-gx,EPSF),  th=fmaxf(gw-gy,EPSF);
    float inter = fmaxf(fminf(px2,gz)-fmaxf(px1,gx),0.f)*fmaxf(fminf(py2,gw)-fmaxf(py1,gy),0.f);
    float uni = pw*ph + tw*th - inter + EPSF;
    float iou = inter/uni;
    float dcx = (px1+px2)*0.5f - (gx+gz)*0.5f;
    float dcy = (py1+py2)*0.5f - (gy+gw)*0.5f;
    float cd = dcx*dcx + dcy*dcy;
    float cw = fmaxf(px2,gz) - fminf(px1,gx);
    float ch = fmaxf(py2,gw) - fminf(py1,gy);
    float c2 = cw*cw + ch*ch + EPSF;
    float dv = atanf(tw/th) - atanf(pw/ph);
    float v  = (4.f/(PIF*PIF))*dv*dv;
    float alpha = v/(v - iou + 1.f + EPSF);
    float ciou = iou - cd/c2 - alpha*v;
    local_box = 1.f - ciou;

    int lab = sl[img][j];
    bool dup = false;
    for (int j2=0; j2<j; j2++)
      if (sm[img][j2]==m && sl[img][j2]==lab){ dup=true; break; }
    if (!dup){
      float x = anchor_base(p0,p1,p2,img,m)[4+lab];
      float s  = fsigm(x);
      float u  = fexp2(-fabsf(x)*LOG2E);
      float lt = LN2*flog2(1.0f + u);
      float sp_pos = fmaxf(-x,0.f) + lt;   // softplus(-x) = ce for tgt=1
      float sp_neg = fmaxf( x,0.f) + lt;   // softplus(x)  = ce for tgt=0
      local_corr = 0.25f*sp_pos*(1.f-s)*(1.f-s) - 0.75f*sp_neg*s*s;
    }
  }
  float local_f = fsum[tid] + fsum[tid + 1024];
  #pragma unroll
  for (int off=32; off>0; off>>=1){
    local_box  += __shfl_xor(local_box,  off);
    local_corr += __shfl_xor(local_corr, off);
    local_f    += __shfl_xor(local_f,    off);
  }
  if (lane == 0){ wb[wid]=local_box; wc[wid]=local_corr; wf[wid]=local_f; }
  __syncthreads();
  if (tid == 0){
    float sb=0.f, sc=0.f, sf=0.f;
    #pragma unroll
    for (int k=0;k<NB;k++){ sb+=wb[k]; sc+=wc[k]; sf+=wf[k]; }
    out[0] = (7.5f*sb + 0.5f*(sf + sc)) / (60.f*16.f);
  }
}

extern "C" void kernel_launch(void* const* d_in, const int* in_sizes, int n_in,
                              void* d_out, int out_size, void* d_ws, size_t ws_size,
                              hipStream_t stream){
  const float* p0 = (const float*)d_in[0];
  const float* p1 = (const float*)d_in[1];
  const float* p2 = (const float*)d_in[2];
  const float* gt = (const float*)d_in[3];
  const int* labels = (const int*)d_in[4];
  float* out = (float*)d_out;

  float4* boxes   = (float4*)d_ws;                                        // 2.15 MB
  int*    cand    = (int*)((char*)d_ws + (size_t)NB*NA*sizeof(float4));   // 38.4 KB
  int*    matched = (int*)((char*)cand + (size_t)NB*NCAND*sizeof(int));   // 3.8 KB
  float*  fsum    = (float*)((char*)matched + (size_t)NB*NGT*sizeof(int));// 8 KB

  fused_decode_focal<<<FOCAL_BLOCKS, 256, 0, stream>>>(p0, p1, p2, boxes, fsum);
  topk_kernel<<<NB*NGT/4, 256, 0, stream>>>(boxes, gt, cand);
  match_kernel<<<NB*NGT, 256, 0, stream>>>(boxes, cand, gt, labels, p0, p1, p2, matched);
  tail_kernel<<<1, 1024, 0, stream>>>(boxes, matched, gt, labels, p0, p1, p2, fsum, out);
}

// Round 8
// 43.149 us; speedup vs baseline: 1.8992x; 1.0770x over previous
//
#include <hip/hip_runtime.h>
#include <cfloat>
#include <math.h>

#define NB   16
#define NGT  60
#define NA   8400
#define KNN  10
#define NCAND (NGT*KNN)   // 600
#define EPSF 1e-7f
#define PIF  3.14159265358979f
#define FOCAL_BLOCKS 2048
#define TOPK_BLOCKS  240   // 960 pairs / 4 waves

// vec4 index space over (p0,p1,p2) concatenated: 2,822,400 vec4s total.
// multiples of 21 are row starts (box channels, skipped); rest -> focal.
#define NV0   2150400u
#define NV1    537600u
#define NV2    134400u
#define FOCAL_COUNT 2688000u  // 20/21 of total

#define LOG2E 1.44269504088896341f
#define LN2   0.69314718055994531f

__device__ __forceinline__ float fexp2(float x){ return __builtin_amdgcn_exp2f(x); }
__device__ __forceinline__ float flog2(float x){ return __builtin_amdgcn_logf(x); }
__device__ __forceinline__ float frcp (float x){ return __builtin_amdgcn_rcpf(x); }

__device__ __forceinline__ float fsigm(float x){
  return frcp(1.0f + fexp2(-x*LOG2E));
}
__device__ __forceinline__ float fsoftplus(float x){
  float u = fexp2(-fabsf(x)*LOG2E);
  return fmaxf(x,0.f) + LN2*flog2(1.0f + u);
}
// fbg = softplus(x)*sigmoid(x)^2 = (x + ln(1+u)) / (1+u)^2,  u = e^-x
__device__ __forceinline__ float fbg(float x){
  float u = fexp2(fminf(-x*LOG2E, 126.0f));
  float t = frcp(1.0f + u);
  return (x + LN2*flog2(1.0f + u)) * t * t;
}

// row pointer + grid coords for an anchor id (decode-on-demand)
struct ARow { const float* q; float stf; int i, j; };
__device__ __forceinline__ ARow anchor_row(const float* p0,const float* p1,const float* p2,int img,int a){
  ARow r;
  if (a < 6400){ int l=a;      r.q = p0 + (size_t)(img*6400 + l)*84; r.stf= 8.f; r.i=l/80; r.j=l-80*r.i; }
  else if (a < 8000){ int l=a-6400; r.q = p1 + (size_t)(img*1600 + l)*84; r.stf=16.f; r.i=l/40; r.j=l-40*r.i; }
  else { int l=a-8000;         r.q = p2 + (size_t)(img*400  + l)*84; r.stf=32.f; r.i=l/20; r.j=l-20*r.i; }
  return r;
}
__device__ __forceinline__ float4 decode_box_xywh(const ARow& r){
  float4 x4 = *(const float4*)r.q;
  float px = (fsigm(x4.x)*2.f - 0.5f + (float)r.j)*r.stf;
  float py = (fsigm(x4.y)*2.f - 0.5f + (float)r.i)*r.stf;
  float pw = fsoftplus(x4.z)*r.stf;
  float ph = fsoftplus(x4.w)*r.stf;
  return make_float4(px,py,pw,ph);
}

// merged kernel: blocks [0,240) do exact windowed top-10 (decode centers on
// demand); blocks [240, 2288) stream the background focal sum.
// Window-prune proof: the 16 L0 anchors in the 4x4 block around the GT center
// have dist^2 <= 28^2+28^2 = 1568, so d10 <= 1568; any anchor outside the
// 13x13/7x7/5x5 windows has min-possible dist^2 > 1568.
__global__ __launch_bounds__(256) void focal_topk_kernel(const float* __restrict__ p0,
                                                         const float* __restrict__ p1,
                                                         const float* __restrict__ p2,
                                                         const float* __restrict__ gt,
                                                         int* __restrict__ cand,
                                                         float* __restrict__ fsum){
  if (blockIdx.x < TOPK_BLOCKS){
    int wid  = threadIdx.x >> 6;
    int lane = threadIdx.x & 63;
    int pair = blockIdx.x*4 + wid;          // 0..959
    int img = pair / NGT, g = pair - img*NGT;
    const float* gb = gt + (size_t)(img*NGT + g)*4;
    float tcx = (gb[0]+gb[2])*0.5f, tcy = (gb[1]+gb[3])*0.5f;

    int jx0 = (int)(tcx * 0.125f),   iy0 = (int)(tcy * 0.125f);
    int jx1 = (int)(tcx * 0.0625f),  iy1 = (int)(tcy * 0.0625f);
    int jx2 = (int)(tcx * 0.03125f), iy2 = (int)(tcy * 0.03125f);

    float d0=FLT_MAX,d1=FLT_MAX,d2=FLT_MAX,d3=FLT_MAX;
    int   a0,a1,a2,a3;
    #pragma unroll
    for (int s=0; s<4; s++){
      int c = lane + 64*s;
      float dd = FLT_MAX; int aa = 9000000 + c;
      const float* p; int i, j, S, base, rowmul, valid = 1; float stf;
      if (c < 169)      { int r=c/13,  q=c-13*r;           i=iy0-6+r; j=jx0-6+q; S=80; base=0;    p=p0; rowmul=6400; stf= 8.f; }
      else if (c < 218) { int t=c-169; int r=t/7, q=t-7*r; i=iy1-3+r; j=jx1-3+q; S=40; base=6400; p=p1; rowmul=1600; stf=16.f; }
      else if (c < 243) { int t=c-218; int r=t/5, q=t-5*r; i=iy2-2+r; j=jx2-2+q; S=20; base=8000; p=p2; rowmul=400;  stf=32.f; }
      else { valid = 0; i=j=0; S=1; base=0; p=p0; rowmul=0; stf=0.f; }
      if (valid && i>=0 && i<S && j>=0 && j<S){
        int local = i*S + j;
        const float* q4 = p + (size_t)(img*rowmul + local)*84u;
        float2 xy = *(const float2*)q4;
        float px = (fsigm(xy.x)*2.f - 0.5f + (float)j)*stf;
        float py = (fsigm(xy.y)*2.f - 0.5f + (float)i)*stf;
        float dx=px-tcx, dy=py-tcy;
        dd = dx*dx + dy*dy;
        aa = base + local;
      }
      if (s==0){ d0=dd; a0=aa; } else if (s==1){ d1=dd; a1=aa; }
      else if (s==2){ d2=dd; a2=aa; } else { d3=dd; a3=aa; }
    }

    for (int r=0; r<KNN; r++){
      float v = d0; int anc = a0;
      if (d1 < v || (d1==v && a1<anc)){ v=d1; anc=a1; }
      if (d2 < v || (d2==v && a2<anc)){ v=d2; anc=a2; }
      if (d3 < v || (d3==v && a3<anc)){ v=d3; anc=a3; }
      #pragma unroll
      for (int off=32; off>0; off>>=1){
        float v2 = __shfl_xor(v, off);
        int  A2 = __shfl_xor(anc, off);
        if (v2 < v || (v2==v && A2<anc)){ v=v2; anc=A2; }
      }
      if (a0==anc) d0=FLT_MAX;
      if (a1==anc) d1=FLT_MAX;
      if (a2==anc) d2=FLT_MAX;
      if (a3==anc) d3=FLT_MAX;
      if (lane == 0) cand[(size_t)pair*KNN + r] = anc;
    }
    return;
  }

  // ---- focal blocks ----
  __shared__ float sbuf[4];
  float sum = 0.f;
  const unsigned stride = FOCAL_BLOCKS*256u;
  for (unsigned u = (blockIdx.x - TOPK_BLOCKS)*256u + threadIdx.x; u < FOCAL_COUNT; u += stride){
    // class vec4: v = 21*(u/20) + u%20 + 1  (never a row start)
    unsigned g = u / 20u;
    unsigned v = 21u*g + (u - 20u*g) + 1u;
    const float* p; unsigned vloc;
    if (v < NV0)           { p=p0; vloc = v; }
    else if (v < NV0+NV1)  { p=p1; vloc = v - NV0; }
    else                   { p=p2; vloc = v - (NV0+NV1); }
    float4 x4 = *(const float4*)(p + (size_t)vloc*4u);
    sum += fbg(x4.x) + fbg(x4.y) + fbg(x4.z) + fbg(x4.w);
  }
  sum *= 0.75f;
  #pragma unroll
  for (int off=32; off>0; off>>=1) sum += __shfl_xor(sum, off);
  int wid = threadIdx.x >> 6;
  if ((threadIdx.x & 63) == 0) sbuf[wid] = sum;
  __syncthreads();
  if (threadIdx.x == 0) fsum[blockIdx.x - TOPK_BLOCKS] = sbuf[0]+sbuf[1]+sbuf[2]+sbuf[3];
}

// one BLOCK per (img,gt): 256 threads scan 600 candidates (decode-on-demand;
// box + logit come from the same 336B row -> L2-local)
__global__ __launch_bounds__(256) void match_kernel(const int* __restrict__ cand,
                                                    const float* __restrict__ gt,
                                                    const int* __restrict__ labels,
                                                    const float* __restrict__ p0,
                                                    const float* __restrict__ p1,
                                                    const float* __restrict__ p2,
                                                    int* __restrict__ matched){
  int pair = blockIdx.x;
  int img = pair / NGT, j = pair - img*NGT;
  int tid = threadIdx.x;
  int wid = tid >> 6, lane = tid & 63;
  const float* gb = gt + (size_t)(img*NGT + j)*4;
  float gx=gb[0], gy=gb[1], gz=gb[2], gw=gb[3];
  float a2 = fmaxf(gz-gx,0.f)*fmaxf(gw-gy,0.f);
  int lab = labels[img*NGT + j];

  const int* ci = cand + (size_t)img*NCAND;
  float best = FLT_MAX; int bslot = 1<<30; int banchor = -1;
  for (int c=tid; c<NCAND; c+=256){
    int a = ci[c];
    ARow ar = anchor_row(p0,p1,p2,img,a);
    float4 b = decode_box_xywh(ar);
    float bx1=b.x-b.z*0.5f, by1=b.y-b.w*0.5f, bx2=b.x+b.z*0.5f, by2=b.y+b.w*0.5f;
    float a1 = fmaxf(bx2-bx1,0.f)*fmaxf(by2-by1,0.f);
    float ix1=fmaxf(bx1,gx), iy1=fmaxf(by1,gy);
    float ix2=fminf(bx2,gz), iy2=fminf(by2,gw);
    float inter = fmaxf(ix2-ix1,0.f)*fmaxf(iy2-iy1,0.f);
    float uni = a1 + a2 - inter + EPSF;
    float iou = fminf(fmaxf(inter/uni,0.f),1.f);
    float lg = ar.q[4+lab];
    float cost = 0.5f*(1.f - fsigm(lg)) + 6.f*(1.f - iou);
    if (cost < best){ best=cost; bslot=c; banchor=a; }
  }
  #pragma unroll
  for (int off=32; off>0; off>>=1){
    float v2 = __shfl_xor(best, off);
    int  s2 = __shfl_xor(bslot, off);
    int  a2s= __shfl_xor(banchor, off);
    if (v2 < best || (v2==best && s2<bslot)){ best=v2; bslot=s2; banchor=a2s; }
  }
  __shared__ float bc[4]; __shared__ int bs[4], ba[4];
  if (lane == 0){ bc[wid]=best; bs[wid]=bslot; ba[wid]=banchor; }
  __syncthreads();
  if (tid == 0){
    float v=bc[0]; int s=bs[0]; int a=ba[0];
    #pragma unroll
    for (int k=1;k<4;k++){
      if (bc[k] < v || (bc[k]==v && bs[k]<s)){ v=bc[k]; s=bs[k]; a=ba[k]; }
    }
    matched[img*NGT + j] = a;
  }
}

// single block, 16 waves (one image each): ciou + dedup'd corrections + focal
// partial reduction + final scalar
__global__ __launch_bounds__(1024) void tail_kernel(const int* __restrict__ matched_g,
                                                    const float* __restrict__ gt,
                                                    const int* __restrict__ labels,
                                                    const float* __restrict__ p0,
                                                    const float* __restrict__ p1,
                                                    const float* __restrict__ p2,
                                                    const float* __restrict__ fsum,
                                                    float* __restrict__ out){
  int tid = threadIdx.x;
  int wid = tid >> 6;        // image
  int lane = tid & 63;
  __shared__ int sm[NB][NGT];
  __shared__ int sl[NB][NGT];
  __shared__ float wb[NB], wc[NB], wf[NB];
  if (lane < NGT){
    sm[wid][lane] = matched_g[wid*NGT + lane];
    sl[wid][lane] = labels[wid*NGT + lane];
  }
  __syncthreads();

  int img = wid;
  float local_box = 0.f, local_corr = 0.f;
  if (lane < NGT){
    int j = lane;
    int m = sm[img][j];
    ARow ar = anchor_row(p0,p1,p2,img,m);
    float4 pb = decode_box_xywh(ar);
    float px1=pb.x-pb.z*0.5f, py1=pb.y-pb.w*0.5f, px2=pb.x+pb.z*0.5f, py2=pb.y+pb.w*0.5f;
    const float* gb = gt + (size_t)(img*NGT + j)*4;
    float gx=gb[0], gy=gb[1], gz=gb[2], gw=gb[3];
    float pw=fmaxf(px2-px1,EPSF), ph=fmaxf(py2-py1,EPSF);
    float tw=fmaxf(gz-gx,EPSF),  th=fmaxf(gw-gy,EPSF);
    float inter = fmaxf(fminf(px2,gz)-fmaxf(px1,gx),0.f)*fmaxf(fminf(py2,gw)-fmaxf(py1,gy),0.f);
    float uni = pw*ph + tw*th - inter + EPSF;
    float iou = inter/uni;
    float dcx = (px1+px2)*0.5f - (gx+gz)*0.5f;
    float dcy = (py1+py2)*0.5f - (gy+gw)*0.5f;
    float cd = dcx*dcx + dcy*dcy;
    float cw = fmaxf(px2,gz) - fminf(px1,gx);
    float ch = fmaxf(py2,gw) - fminf(py1,gy);
    float c2 = cw*cw + ch*ch + EPSF;
    float dv = atanf(tw/th) - atanf(pw/ph);
    float v  = (4.f/(PIF*PIF))*dv*dv;
    float alpha = v/(v - iou + 1.f + EPSF);
    float ciou = iou - cd/c2 - alpha*v;
    local_box = 1.f - ciou;

    int lab = sl[img][j];
    bool dup = false;
    for (int j2=0; j2<j; j2++)
      if (sm[img][j2]==m && sl[img][j2]==lab){ dup=true; break; }
    if (!dup){
      float x = ar.q[4+lab];
      float s  = fsigm(x);
      float u  = fexp2(-fabsf(x)*LOG2E);
      float lt = LN2*flog2(1.0f + u);
      float sp_pos = fmaxf(-x,0.f) + lt;   // ce for tgt=1
      float sp_neg = fmaxf( x,0.f) + lt;   // ce for tgt=0
      local_corr = 0.25f*sp_pos*(1.f-s)*(1.f-s) - 0.75f*sp_neg*s*s;
    }
  }
  float local_f = fsum[tid] + fsum[tid + 1024];
  #pragma unroll
  for (int off=32; off>0; off>>=1){
    local_box  += __shfl_xor(local_box,  off);
    local_corr += __shfl_xor(local_corr, off);
    local_f    += __shfl_xor(local_f,    off);
  }
  if (lane == 0){ wb[wid]=local_box; wc[wid]=local_corr; wf[wid]=local_f; }
  __syncthreads();
  if (tid == 0){
    float sb=0.f, sc=0.f, sf=0.f;
    #pragma unroll
    for (int k=0;k<NB;k++){ sb+=wb[k]; sc+=wc[k]; sf+=wf[k]; }
    out[0] = (7.5f*sb + 0.5f*(sf + sc)) / (60.f*16.f);
  }
}

extern "C" void kernel_launch(void* const* d_in, const int* in_sizes, int n_in,
                              void* d_out, int out_size, void* d_ws, size_t ws_size,
                              hipStream_t stream){
  const float* p0 = (const float*)d_in[0];
  const float* p1 = (const float*)d_in[1];
  const float* p2 = (const float*)d_in[2];
  const float* gt = (const float*)d_in[3];
  const int* labels = (const int*)d_in[4];
  float* out = (float*)d_out;

  int*   cand    = (int*)d_ws;                                            // 38.4 KB
  int*   matched = (int*)((char*)cand + (size_t)NB*NCAND*sizeof(int));    // 3.8 KB
  float* fsum    = (float*)((char*)matched + (size_t)NB*NGT*sizeof(int)); // 8 KB

  focal_topk_kernel<<<TOPK_BLOCKS + FOCAL_BLOCKS, 256, 0, stream>>>(p0, p1, p2, gt, cand, fsum);
  match_kernel<<<NB*NGT, 256, 0, stream>>>(cand, gt, labels, p0, p1, p2, matched);
  tail_kernel<<<1, 1024, 0, stream>>>(matched, gt, labels, p0, p1, p2, fsum, out);
}

// Round 9
// 43.034 us; speedup vs baseline: 1.9042x; 1.0027x over previous
//
#include <hip/hip_runtime.h>
#include <cfloat>
#include <math.h>

#define NB   16
#define NGT  60
#define NA   8400
#define KNN  10
#define NCAND (NGT*KNN)   // 600
#define EPSF 1e-7f
#define PIF  3.14159265358979f
#define MATCH_BLOCKS 960
#define FOCAL_BLOCKS 2100   // 2,688,000 / (2100*256) = exactly 5 iters/thread
#define TOPK_BLOCKS  240    // 960 pairs / 4 waves

// vec4 index space over (p0,p1,p2) concatenated: 2,822,400 vec4s total.
// multiples of 21 are row starts (box channels, skipped); rest -> focal.
#define NV0   2150400u
#define NV1    537600u
#define NV2    134400u
#define FOCAL_COUNT 2688000u  // 20/21 of total

#define LOG2E 1.44269504088896341f
#define LN2   0.69314718055994531f

__device__ __forceinline__ float fexp2(float x){ return __builtin_amdgcn_exp2f(x); }
__device__ __forceinline__ float flog2(float x){ return __builtin_amdgcn_logf(x); }
__device__ __forceinline__ float frcp (float x){ return __builtin_amdgcn_rcpf(x); }

__device__ __forceinline__ float fsigm(float x){
  return frcp(1.0f + fexp2(-x*LOG2E));
}
__device__ __forceinline__ float fsoftplus(float x){
  float u = fexp2(-fabsf(x)*LOG2E);
  return fmaxf(x,0.f) + LN2*flog2(1.0f + u);
}
// fbg = softplus(x)*sigmoid(x)^2 = (x + ln(1+u)) / (1+u)^2,  u = e^-x
__device__ __forceinline__ float fbg(float x){
  float u = fexp2(fminf(-x*LOG2E, 126.0f));
  float t = frcp(1.0f + u);
  return (x + LN2*flog2(1.0f + u)) * t * t;
}

// row pointer + grid coords for an anchor id (decode-on-demand)
struct ARow { const float* q; float stf; int i, j; };
__device__ __forceinline__ ARow anchor_row(const float* p0,const float* p1,const float* p2,int img,int a){
  ARow r;
  if (a < 6400){ int l=a;      r.q = p0 + (size_t)(img*6400 + l)*84; r.stf= 8.f; r.i=l/80; r.j=l-80*r.i; }
  else if (a < 8000){ int l=a-6400; r.q = p1 + (size_t)(img*1600 + l)*84; r.stf=16.f; r.i=l/40; r.j=l-40*r.i; }
  else { int l=a-8000;         r.q = p2 + (size_t)(img*400  + l)*84; r.stf=32.f; r.i=l/20; r.j=l-20*r.i; }
  return r;
}
__device__ __forceinline__ float4 decode_box_xywh(const ARow& r){
  float4 x4 = *(const float4*)r.q;
  float px = (fsigm(x4.x)*2.f - 0.5f + (float)r.j)*r.stf;
  float py = (fsigm(x4.y)*2.f - 0.5f + (float)r.i)*r.stf;
  float pw = fsoftplus(x4.z)*r.stf;
  float ph = fsoftplus(x4.w)*r.stf;
  return make_float4(px,py,pw,ph);
}

// one wave per (img,gt), 4 waves/block. Exact top-10 from pruned windows:
// 13x13 (L0) + 7x7 (L1) + 5x5 (L2) = 243 candidates. d10 <= 1568 provably
// (16 L0 anchors in the 4x4 block around the GT center are within 28px/axis);
// anything outside the windows has min-possible dist^2 > 1568.
__global__ __launch_bounds__(256) void topk_kernel(const float* __restrict__ p0,
                                                   const float* __restrict__ p1,
                                                   const float* __restrict__ p2,
                                                   const float* __restrict__ gt,
                                                   int* __restrict__ cand){
  int wid  = threadIdx.x >> 6;
  int lane = threadIdx.x & 63;
  int pair = blockIdx.x*4 + wid;          // 0..959
  int img = pair / NGT, g = pair - img*NGT;
  const float* gb = gt + (size_t)(img*NGT + g)*4;
  float tcx = (gb[0]+gb[2])*0.5f, tcy = (gb[1]+gb[3])*0.5f;

  int jx0 = (int)(tcx * 0.125f),   iy0 = (int)(tcy * 0.125f);
  int jx1 = (int)(tcx * 0.0625f),  iy1 = (int)(tcy * 0.0625f);
  int jx2 = (int)(tcx * 0.03125f), iy2 = (int)(tcy * 0.03125f);

  float d0=FLT_MAX,d1=FLT_MAX,d2=FLT_MAX,d3=FLT_MAX;
  int   a0,a1,a2,a3;
  #pragma unroll
  for (int s=0; s<4; s++){
    int c = lane + 64*s;
    float dd = FLT_MAX; int aa = 9000000 + c;
    const float* p; int i, j, S, base, rowmul, valid = 1; float stf;
    if (c < 169)      { int r=c/13,  q=c-13*r;           i=iy0-6+r; j=jx0-6+q; S=80; base=0;    p=p0; rowmul=6400; stf= 8.f; }
    else if (c < 218) { int t=c-169; int r=t/7, q=t-7*r; i=iy1-3+r; j=jx1-3+q; S=40; base=6400; p=p1; rowmul=1600; stf=16.f; }
    else if (c < 243) { int t=c-218; int r=t/5, q=t-5*r; i=iy2-2+r; j=jx2-2+q; S=20; base=8000; p=p2; rowmul=400;  stf=32.f; }
    else { valid = 0; i=j=0; S=1; base=0; p=p0; rowmul=0; stf=0.f; }
    if (valid && i>=0 && i<S && j>=0 && j<S){
      int local = i*S + j;
      const float* q4 = p + (size_t)(img*rowmul + local)*84u;
      float2 xy = *(const float2*)q4;
      float px = (fsigm(xy.x)*2.f - 0.5f + (float)j)*stf;
      float py = (fsigm(xy.y)*2.f - 0.5f + (float)i)*stf;
      float dx=px-tcx, dy=py-tcy;
      dd = dx*dx + dy*dy;
      aa = base + local;
    }
    if (s==0){ d0=dd; a0=aa; } else if (s==1){ d1=dd; a1=aa; }
    else if (s==2){ d2=dd; a2=aa; } else { d3=dd; a3=aa; }
  }

  for (int r=0; r<KNN; r++){
    float v = d0; int anc = a0;
    if (d1 < v || (d1==v && a1<anc)){ v=d1; anc=a1; }
    if (d2 < v || (d2==v && a2<anc)){ v=d2; anc=a2; }
    if (d3 < v || (d3==v && a3<anc)){ v=d3; anc=a3; }
    #pragma unroll
    for (int off=32; off>0; off>>=1){
      float v2 = __shfl_xor(v, off);
      int  A2 = __shfl_xor(anc, off);
      if (v2 < v || (v2==v && A2<anc)){ v=v2; anc=A2; }
    }
    if (a0==anc) d0=FLT_MAX;
    if (a1==anc) d1=FLT_MAX;
    if (a2==anc) d2=FLT_MAX;
    if (a3==anc) d3=FLT_MAX;
    if (lane == 0) cand[(size_t)pair*KNN + r] = anc;
  }
}

// merged kernel: blocks [0,960) do match (XCD-swizzled: img = blk&15 so an
// image's 60 blocks co-locate on ~2 XCD L2s); blocks [960, 3060) stream the
// background focal sum. The two halves are independent -> they overlap.
__global__ __launch_bounds__(256) void focal_match_kernel(const float* __restrict__ p0,
                                                          const float* __restrict__ p1,
                                                          const float* __restrict__ p2,
                                                          const float* __restrict__ gt,
                                                          const int* __restrict__ labels,
                                                          const int* __restrict__ cand,
                                                          int* __restrict__ matched,
                                                          float* __restrict__ fsum){
  if (blockIdx.x < MATCH_BLOCKS){
    int img = blockIdx.x & 15;            // XCD locality: same img -> same mod-16 class
    int j   = blockIdx.x >> 4;            // 0..59
    int tid = threadIdx.x;
    int wid = tid >> 6, lane = tid & 63;
    const float* gb = gt + (size_t)(img*NGT + j)*4;
    float gx=gb[0], gy=gb[1], gz=gb[2], gw=gb[3];
    float a2 = fmaxf(gz-gx,0.f)*fmaxf(gw-gy,0.f);
    int lab = labels[img*NGT + j];

    const int* ci = cand + (size_t)img*NCAND;
    float best = FLT_MAX; int bslot = 1<<30; int banchor = -1;
    for (int c=tid; c<NCAND; c+=256){
      int a = ci[c];
      ARow ar = anchor_row(p0,p1,p2,img,a);
      float4 b = decode_box_xywh(ar);
      float bx1=b.x-b.z*0.5f, by1=b.y-b.w*0.5f, bx2=b.x+b.z*0.5f, by2=b.y+b.w*0.5f;
      float a1 = fmaxf(bx2-bx1,0.f)*fmaxf(by2-by1,0.f);
      float ix1=fmaxf(bx1,gx), iy1=fmaxf(by1,gy);
      float ix2=fminf(bx2,gz), iy2=fminf(by2,gw);
      float inter = fmaxf(ix2-ix1,0.f)*fmaxf(iy2-iy1,0.f);
      float uni = a1 + a2 - inter + EPSF;
      float iou = fminf(fmaxf(inter/uni,0.f),1.f);
      float lg = ar.q[4+lab];
      float cost = 0.5f*(1.f - fsigm(lg)) + 6.f*(1.f - iou);
      if (cost < best){ best=cost; bslot=c; banchor=a; }
    }
    #pragma unroll
    for (int off=32; off>0; off>>=1){
      float v2 = __shfl_xor(best, off);
      int  s2 = __shfl_xor(bslot, off);
      int  a2s= __shfl_xor(banchor, off);
      if (v2 < best || (v2==best && s2<bslot)){ best=v2; bslot=s2; banchor=a2s; }
    }
    __shared__ float bc[4]; __shared__ int bs[4], ba[4];
    if (lane == 0){ bc[wid]=best; bs[wid]=bslot; ba[wid]=banchor; }
    __syncthreads();
    if (tid == 0){
      float v=bc[0]; int s=bs[0]; int a=ba[0];
      #pragma unroll
      for (int k=1;k<4;k++){
        if (bc[k] < v || (bc[k]==v && bs[k]<s)){ v=bc[k]; s=bs[k]; a=ba[k]; }
      }
      matched[img*NGT + j] = a;
    }
    return;
  }

  // ---- focal blocks ----
  __shared__ float sbuf[4];
  float sum = 0.f;
  const unsigned stride = FOCAL_BLOCKS*256u;
  for (unsigned u = (blockIdx.x - MATCH_BLOCKS)*256u + threadIdx.x; u < FOCAL_COUNT; u += stride){
    // class vec4: v = 21*(u/20) + u%20 + 1  (never a row start)
    unsigned g = u / 20u;
    unsigned v = 21u*g + (u - 20u*g) + 1u;
    const float* p; unsigned vloc;
    if (v < NV0)           { p=p0; vloc = v; }
    else if (v < NV0+NV1)  { p=p1; vloc = v - NV0; }
    else                   { p=p2; vloc = v - (NV0+NV1); }
    float4 x4 = *(const float4*)(p + (size_t)vloc*4u);
    sum += fbg(x4.x) + fbg(x4.y) + fbg(x4.z) + fbg(x4.w);
  }
  sum *= 0.75f;
  #pragma unroll
  for (int off=32; off>0; off>>=1) sum += __shfl_xor(sum, off);
  int wid = threadIdx.x >> 6;
  if ((threadIdx.x & 63) == 0) sbuf[wid] = sum;
  __syncthreads();
  if (threadIdx.x == 0) fsum[blockIdx.x - MATCH_BLOCKS] = sbuf[0]+sbuf[1]+sbuf[2]+sbuf[3];
}

// single block, 16 waves (one image each): ciou + dedup'd corrections + focal
// partial reduction + final scalar
__global__ __launch_bounds__(1024) void tail_kernel(const int* __restrict__ matched_g,
                                                    const float* __restrict__ gt,
                                                    const int* __restrict__ labels,
                                                    const float* __restrict__ p0,
                                                    const float* __restrict__ p1,
                                                    const float* __restrict__ p2,
                                                    const float* __restrict__ fsum,
                                                    float* __restrict__ out){
  int tid = threadIdx.x;
  int wid = tid >> 6;        // image
  int lane = tid & 63;
  __shared__ int sm[NB][NGT];
  __shared__ int sl[NB][NGT];
  __shared__ float wb[NB], wc[NB], wf[NB];
  if (lane < NGT){
    sm[wid][lane] = matched_g[wid*NGT + lane];
    sl[wid][lane] = labels[wid*NGT + lane];
  }
  __syncthreads();

  int img = wid;
  float local_box = 0.f, local_corr = 0.f;
  if (lane < NGT){
    int j = lane;
    int m = sm[img][j];
    ARow ar = anchor_row(p0,p1,p2,img,m);
    float4 pb = decode_box_xywh(ar);
    float px1=pb.x-pb.z*0.5f, py1=pb.y-pb.w*0.5f, px2=pb.x+pb.z*0.5f, py2=pb.y+pb.w*0.5f;
    const float* gb = gt + (size_t)(img*NGT + j)*4;
    float gx=gb[0], gy=gb[1], gz=gb[2], gw=gb[3];
    float pw=fmaxf(px2-px1,EPSF), ph=fmaxf(py2-py1,EPSF);
    float tw=fmaxf(gz-gx,EPSF),  th=fmaxf(gw-gy,EPSF);
    float inter = fmaxf(fminf(px2,gz)-fmaxf(px1,gx),0.f)*fmaxf(fminf(py2,gw)-fmaxf(py1,gy),0.f);
    float uni = pw*ph + tw*th - inter + EPSF;
    float iou = inter/uni;
    float dcx = (px1+px2)*0.5f - (gx+gz)*0.5f;
    float dcy = (py1+py2)*0.5f - (gy+gw)*0.5f;
    float cd = dcx*dcx + dcy*dcy;
    float cw = fmaxf(px2,gz) - fminf(px1,gx);
    float ch = fmaxf(py2,gw) - fminf(py1,gy);
    float c2 = cw*cw + ch*ch + EPSF;
    float dv = atanf(tw/th) - atanf(pw/ph);
    float v  = (4.f/(PIF*PIF))*dv*dv;
    float alpha = v/(v - iou + 1.f + EPSF);
    float ciou = iou - cd/c2 - alpha*v;
    local_box = 1.f - ciou;

    int lab = sl[img][j];
    bool dup = false;
    for (int j2=0; j2<j; j2++)
      if (sm[img][j2]==m && sl[img][j2]==lab){ dup=true; break; }
    if (!dup){
      float x = ar.q[4+lab];
      float s  = fsigm(x);
      float u  = fexp2(-fabsf(x)*LOG2E);
      float lt = LN2*flog2(1.0f + u);
      float sp_pos = fmaxf(-x,0.f) + lt;   // ce for tgt=1
      float sp_neg = fmaxf( x,0.f) + lt;   // ce for tgt=0
      local_corr = 0.25f*sp_pos*(1.f-s)*(1.f-s) - 0.75f*sp_neg*s*s;
    }
  }
  float local_f = fsum[tid] + fsum[tid + 1024];
  if (tid < FOCAL_BLOCKS - 2048) local_f += fsum[tid + 2048];
  #pragma unroll
  for (int off=32; off>0; off>>=1){
    local_box  += __shfl_xor(local_box,  off);
    local_corr += __shfl_xor(local_corr, off);
    local_f    += __shfl_xor(local_f,    off);
  }
  if (lane == 0){ wb[wid]=local_box; wc[wid]=local_corr; wf[wid]=local_f; }
  __syncthreads();
  if (tid == 0){
    float sb=0.f, sc=0.f, sf=0.f;
    #pragma unroll
    for (int k=0;k<NB;k++){ sb+=wb[k]; sc+=wc[k]; sf+=wf[k]; }
    out[0] = (7.5f*sb + 0.5f*(sf + sc)) / (60.f*16.f);
  }
}

extern "C" void kernel_launch(void* const* d_in, const int* in_sizes, int n_in,
                              void* d_out, int out_size, void* d_ws, size_t ws_size,
                              hipStream_t stream){
  const float* p0 = (const float*)d_in[0];
  const float* p1 = (const float*)d_in[1];
  const float* p2 = (const float*)d_in[2];
  const float* gt = (const float*)d_in[3];
  const int* labels = (const int*)d_in[4];
  float* out = (float*)d_out;

  int*   cand    = (int*)d_ws;                                            // 38.4 KB
  int*   matched = (int*)((char*)cand + (size_t)NB*NCAND*sizeof(int));    // 3.8 KB
  float* fsum    = (float*)((char*)matched + (size_t)NB*NGT*sizeof(int)); // 8.4 KB

  topk_kernel<<<TOPK_BLOCKS, 256, 0, stream>>>(p0, p1, p2, gt, cand);
  focal_match_kernel<<<MATCH_BLOCKS + FOCAL_BLOCKS, 256, 0, stream>>>(p0, p1, p2, gt, labels,
                                                                      cand, matched, fsum);
  tail_kernel<<<1, 1024, 0, stream>>>(matched, gt, labels, p0, p1, p2, fsum, out);
}